// Round 5
// baseline (888.799 us; speedup 1.0000x reference)
//
#include <hip/hip_runtime.h>

#define TT 512
#define NB 128   // batch
#define DD 128
#define HH 64
#define CC 45

__device__ __forceinline__ float sigf(float x) { return 1.0f / (1.0f + __expf(-x)); }

// ---------------------------------------------------------------------------
// GEMM: Cout[m][0:512] = A[m][0:128] @ [Wf | Wb] + [biasf | biasb]
// A: [65536][128] row-major. Wf/Wb: [128][256] row-major. Cout: [65536][512].
// BM=128, BN=128, BK=32, 256 threads, 8x8 accumulation per thread. f32 VALU.
// ---------------------------------------------------------------------------
__global__ __launch_bounds__(256) void gemm_xz(
    const float* __restrict__ A, const float* __restrict__ Wf,
    const float* __restrict__ Wb, const float* __restrict__ biasf,
    const float* __restrict__ biasb, float* __restrict__ Cout)
{
    __shared__ float As[32][132];   // [k][m], padded
    __shared__ float Bs[32][132];   // [k][n], padded
    const int tid = threadIdx.x;
    const int m0 = blockIdx.x * 128;
    const int n0 = blockIdx.y * 128;          // global col in [0,512)
    const float* W   = (n0 < 256) ? Wf : Wb;
    const float* bia = (n0 < 256) ? biasf : biasb;
    const int nc0 = n0 & 255;

    const int ty = tid >> 4, tx = tid & 15;
    const int arow = tid >> 3, akv = (tid & 7) << 2;
    const int bkr  = tid >> 5, bnv = (tid & 31) << 2;

    float acc[8][8];
    #pragma unroll
    for (int i = 0; i < 8; ++i)
        #pragma unroll
        for (int j = 0; j < 8; ++j) acc[i][j] = 0.f;

    for (int k0 = 0; k0 < 128; k0 += 32) {
        #pragma unroll
        for (int rr = 0; rr < 4; ++rr) {
            const int r = arow + rr * 32;
            const float4 av = *(const float4*)&A[(size_t)(m0 + r) * 128 + k0 + akv];
            As[akv + 0][r] = av.x; As[akv + 1][r] = av.y;
            As[akv + 2][r] = av.z; As[akv + 3][r] = av.w;
        }
        #pragma unroll
        for (int rr = 0; rr < 4; ++rr) {
            const int kr = bkr + rr * 8;
            *(float4*)&Bs[kr][bnv] =
                *(const float4*)&W[(size_t)(k0 + kr) * 256 + nc0 + bnv];
        }
        __syncthreads();
        #pragma unroll
        for (int k = 0; k < 32; ++k) {
            float av[8], bv[8];
            *(float4*)&av[0] = *(const float4*)&As[k][ty * 8];
            *(float4*)&av[4] = *(const float4*)&As[k][ty * 8 + 4];
            *(float4*)&bv[0] = *(const float4*)&Bs[k][tx * 8];
            *(float4*)&bv[4] = *(const float4*)&Bs[k][tx * 8 + 4];
            #pragma unroll
            for (int i = 0; i < 8; ++i)
                #pragma unroll
                for (int j = 0; j < 8; ++j)
                    acc[i][j] = __fmaf_rn(av[i], bv[j], acc[i][j]);
        }
        __syncthreads();
    }
    #pragma unroll
    for (int i = 0; i < 8; ++i) {
        const size_t rbase = (size_t)(m0 + ty * 8 + i) * 512 + n0 + tx * 8;
        float4 o;
        o.x = acc[i][0] + bia[nc0 + tx * 8 + 0];
        o.y = acc[i][1] + bia[nc0 + tx * 8 + 1];
        o.z = acc[i][2] + bia[nc0 + tx * 8 + 2];
        o.w = acc[i][3] + bia[nc0 + tx * 8 + 3];
        *(float4*)&Cout[rbase] = o;
        o.x = acc[i][4] + bia[nc0 + tx * 8 + 4];
        o.y = acc[i][5] + bia[nc0 + tx * 8 + 5];
        o.z = acc[i][6] + bia[nc0 + tx * 8 + 6];
        o.w = acc[i][7] + bia[nc0 + tx * 8 + 7];
        *(float4*)&Cout[rbase + 4] = o;
    }
}

// ---------------------------------------------------------------------------
// LSTM recurrence, K-SPLIT. 256 blocks (batch x dir) x 1024 threads.
// Thread (kq, gate, col): kq = tid>>8, t8 = tid&255, gate = t8&3, col = t8>>2.
// Each thread holds only 16 U values U[kq*16+j][gate*64+col] — small enough
// that the RA keeps them resident at ANY occupancy target (R3/R4 post-mortem:
// with 64 values/lane the RA rematerialized the invariant loads every step ->
// 8.6 GB/dispatch of L2 traffic -> 300us). asm pin makes remat impossible.
// Per step: 16 FMA -> partial to zbuf -> barrier -> kq0 waves reduce (+x),
// gate activation, quad shfl_xor combine (gates adjacent, same wave), c/h
// update, h to hbuf (double-buffered) + global -> barrier.
// ---------------------------------------------------------------------------
__global__ __launch_bounds__(1024, 1) void lstm_rec_ks(
    const float* __restrict__ xz, const float* __restrict__ Uf,
    const float* __restrict__ Ub, float* __restrict__ hout)
{
    const int b   = blockIdx.x & 127;
    const int dir = blockIdx.x >> 7;
    const int tid = threadIdx.x;
    const int t8  = tid & 255;
    const int kq  = tid >> 8;          // K-quarter 0..3 (wave-uniform)
    const int gate = t8 & 3;           // 0:i 1:f 2:g 3:o
    const int col  = t8 >> 2;          // 0..63
    const int gcol = gate * 64 + col;
    const float* U = dir ? Ub : Uf;

    __shared__ float hbuf[2][64];
    __shared__ float zbuf[1024];

    // 16 U values for this thread's K-quarter, pinned into VGPRs.
    const float* Ug = U + (size_t)(kq * 16) * 256 + gcol;
    float u0  = Ug[0 * 256],  u1  = Ug[1 * 256],  u2  = Ug[2 * 256],  u3  = Ug[3 * 256];
    float u4  = Ug[4 * 256],  u5  = Ug[5 * 256],  u6  = Ug[6 * 256],  u7  = Ug[7 * 256];
    float u8  = Ug[8 * 256],  u9  = Ug[9 * 256],  u10 = Ug[10 * 256], u11 = Ug[11 * 256];
    float u12 = Ug[12 * 256], u13 = Ug[13 * 256], u14 = Ug[14 * 256], u15 = Ug[15 * 256];
    asm volatile("" : "+v"(u0), "+v"(u1), "+v"(u2), "+v"(u3),
                      "+v"(u4), "+v"(u5), "+v"(u6), "+v"(u7),
                      "+v"(u8), "+v"(u9), "+v"(u10), "+v"(u11),
                      "+v"(u12), "+v"(u13), "+v"(u14), "+v"(u15));

    if (tid < 64) hbuf[0][tid] = 0.f;
    float c = 0.f;
    __syncthreads();

    const float* xzb = xz + (size_t)b * TT * 512 + (size_t)dir * 256 + gcol;
    float*       hob = hout + (size_t)b * TT * 128 + (size_t)dir * 64 + col;

    int trow = dir ? (TT - 1) : 0;
    const int tstep = dir ? -1 : 1;
    float xc = (kq == 0) ? xzb[(size_t)trow * 512] : 0.f;
    int p = 0;

    for (int s = 0; s < TT; ++s) {
        const int trn = trow + tstep;
        float xn = 0.f;
        if (kq == 0 && s + 1 < TT) xn = xzb[(size_t)trn * 512];  // prefetch x

        // partial dot: this K-quarter of h (wave-uniform LDS broadcast)
        const float* hb = &hbuf[p][kq * 16];
        const float4 h0 = *(const float4*)&hb[0];
        const float4 h1 = *(const float4*)&hb[4];
        const float4 h2 = *(const float4*)&hb[8];
        const float4 h3 = *(const float4*)&hb[12];
        float a0 = 0.f, a1 = 0.f, a2 = 0.f, a3 = 0.f;
        a0 = __fmaf_rn(h0.x, u0,  a0); a1 = __fmaf_rn(h0.y, u1,  a1);
        a2 = __fmaf_rn(h0.z, u2,  a2); a3 = __fmaf_rn(h0.w, u3,  a3);
        a0 = __fmaf_rn(h1.x, u4,  a0); a1 = __fmaf_rn(h1.y, u5,  a1);
        a2 = __fmaf_rn(h1.z, u6,  a2); a3 = __fmaf_rn(h1.w, u7,  a3);
        a0 = __fmaf_rn(h2.x, u8,  a0); a1 = __fmaf_rn(h2.y, u9,  a1);
        a2 = __fmaf_rn(h2.z, u10, a2); a3 = __fmaf_rn(h2.w, u11, a3);
        a0 = __fmaf_rn(h3.x, u12, a0); a1 = __fmaf_rn(h3.y, u13, a1);
        a2 = __fmaf_rn(h3.z, u14, a2); a3 = __fmaf_rn(h3.w, u15, a3);
        zbuf[kq * 256 + t8] = (a0 + a1) + (a2 + a3);
        __syncthreads();

        if (kq == 0) {   // waves 0-3 finish the step
            const float z = xc + ((zbuf[t8] + zbuf[256 + t8]) +
                                  (zbuf[512 + t8] + zbuf[768 + t8]));
            // own gate activation (relu for gate 2, sigmoid otherwise)
            const float a = (gate == 2) ? fmaxf(z, 0.f) : sigf(z);
            // quad all-gather: lanes 4c..4c+3 hold gates 0..3 of column c
            const float b0 = __shfl_xor(a, 1);
            const float b1 = __shfl_xor(a, 2);
            const float b2 = __shfl_xor(b0, 2);
            const float ai = (gate == 0) ? a : (gate == 1) ? b0 : (gate == 2) ? b1 : b2;
            const float af = (gate == 1) ? a : (gate == 0) ? b0 : (gate == 3) ? b1 : b2;
            const float ag = (gate == 2) ? a : (gate == 3) ? b0 : (gate == 0) ? b1 : b2;
            const float ao = (gate == 3) ? a : (gate == 2) ? b0 : (gate == 1) ? b1 : b2;
            c = af * c + ai * ag;                 // ag already relu'd
            const float h = ao * fmaxf(c, 0.f);
            if (gate == 0) {                      // one writer per column
                hbuf[p ^ 1][col] = h;
                hob[(size_t)trow * 128] = h;
            }
        }
        __syncthreads();   // h ready for all waves; WAR safe via parity

        xc = xn;
        trow = trn;
        p ^= 1;
    }
}

// ---------------------------------------------------------------------------
// Dense + softmax: out[m][c] = softmax_c( h2[m][:] @ Wd[:,c] + bd[c] )
// ---------------------------------------------------------------------------
__global__ __launch_bounds__(256) void dense_softmax(
    const float* __restrict__ h2, const float* __restrict__ Wd,
    const float* __restrict__ bd, float* __restrict__ out)
{
    __shared__ float Wl[128 * 45];
    __shared__ float bl[48];
    __shared__ float hrow[4][128];
    const int tid = threadIdx.x;
    for (int i = tid; i < 128 * 45; i += 256) Wl[i] = Wd[i];
    if (tid < 45) bl[tid] = bd[tid];
    __syncthreads();

    const int w = tid >> 6, l = tid & 63;
    const size_t row0 = (size_t)blockIdx.x * 64;
    for (int rr = 0; rr < 16; ++rr) {
        const size_t m = row0 + (size_t)rr * 4 + w;
        const float2 hv = *(const float2*)&h2[m * 128 + l * 2];
        hrow[w][l * 2] = hv.x;
        hrow[w][l * 2 + 1] = hv.y;
        __syncthreads();
        float lg = -3.0e38f;
        if (l < CC) {
            lg = bl[l];
            #pragma unroll 8
            for (int k = 0; k < 128; ++k) lg = __fmaf_rn(hrow[w][k], Wl[k * 45 + l], lg);
        }
        float mx = lg;
        #pragma unroll
        for (int off = 32; off >= 1; off >>= 1) mx = fmaxf(mx, __shfl_xor(mx, off));
        const float e = (l < CC) ? __expf(lg - mx) : 0.f;
        float sm = e;
        #pragma unroll
        for (int off = 32; off >= 1; off >>= 1) sm += __shfl_xor(sm, off);
        if (l < CC) out[m * 45 + l] = e / sm;
        __syncthreads();
    }
}

// ---------------------------------------------------------------------------
extern "C" void kernel_launch(void* const* d_in, const int* in_sizes, int n_in,
                              void* d_out, int out_size, void* d_ws, size_t ws_size,
                              hipStream_t stream)
{
    const float* x   = (const float*)d_in[0];
    const float* W1f = (const float*)d_in[1];
    const float* U1f = (const float*)d_in[2];
    const float* b1f = (const float*)d_in[3];
    const float* W1b = (const float*)d_in[4];
    const float* U1b = (const float*)d_in[5];
    const float* b1b = (const float*)d_in[6];
    const float* W2f = (const float*)d_in[7];
    const float* U2f = (const float*)d_in[8];
    const float* b2f = (const float*)d_in[9];
    const float* W2b = (const float*)d_in[10];
    const float* U2b = (const float*)d_in[11];
    const float* b2b = (const float*)d_in[12];
    const float* Wd  = (const float*)d_in[13];
    const float* bd  = (const float*)d_in[14];

    // Workspace layout (160 MiB):
    //   xz : 65536 x 512 f32 = 128 MiB   (reused by layer 1 and layer 2)
    //   h  : 65536 x 128 f32 =  32 MiB   (h1, then overwritten by h2)
    float* xz = (float*)d_ws;
    float* h  = (float*)((char*)d_ws + (size_t)65536 * 512 * 4);

    const dim3 gemm_grid(512, 4);      // 65536/128 m-tiles, 512/128 n-tiles
    const dim3 rec_grid(256);          // 128 batch x 2 directions
    const dim3 dense_grid(1024);       // 65536/64 rows

    // Layer 1
    gemm_xz<<<gemm_grid, dim3(256), 0, stream>>>(x, W1f, W1b, b1f, b1b, xz);
    lstm_rec_ks<<<rec_grid, dim3(1024), 0, stream>>>(xz, U1f, U1b, h);
    // Layer 2
    gemm_xz<<<gemm_grid, dim3(256), 0, stream>>>(h, W2f, W2b, b2f, b2b, xz);
    lstm_rec_ks<<<rec_grid, dim3(1024), 0, stream>>>(xz, U2f, U2b, h);
    // Head
    dense_softmax<<<dense_grid, dim3(256), 0, stream>>>(h, Wd, bd, (float*)d_out);
}

// Round 6
// 745.977 us; speedup vs baseline: 1.1915x; 1.1915x over previous
//
#include <hip/hip_runtime.h>

#define TT 512
#define NB 128   // batch
#define DD 128
#define HH 64
#define CC 45

__device__ __forceinline__ float sigf(float x) { return 1.0f / (1.0f + __expf(-x)); }

// LDS-only barrier: syncs LDS visibility WITHOUT draining vmcnt.
// __syncthreads() emits s_waitcnt vmcnt(0) lgkmcnt(0) before s_barrier, which
// forces the in-flight xz prefetch loads AND h stores to complete inside every
// step's critical path (~500-900 cyc of HBM/L3 latency x 512 steps) — the
// measured ~1500 cyc/step floor of R0/R3/R4/R5. This barrier waits LDS only.
#define LDS_BAR() asm volatile("s_waitcnt lgkmcnt(0)\n\ts_barrier" ::: "memory")

// ---------------------------------------------------------------------------
// GEMM: Cout[m][0:512] = A[m][0:128] @ [Wf | Wb] + [biasf | biasb]
// A: [65536][128] row-major. Wf/Wb: [128][256] row-major. Cout: [65536][512].
// BM=128, BN=128, BK=32, 256 threads, 8x8 accumulation per thread. f32 VALU.
// ---------------------------------------------------------------------------
__global__ __launch_bounds__(256) void gemm_xz(
    const float* __restrict__ A, const float* __restrict__ Wf,
    const float* __restrict__ Wb, const float* __restrict__ biasf,
    const float* __restrict__ biasb, float* __restrict__ Cout)
{
    __shared__ float As[32][132];   // [k][m], padded
    __shared__ float Bs[32][132];   // [k][n], padded
    const int tid = threadIdx.x;
    const int m0 = blockIdx.x * 128;
    const int n0 = blockIdx.y * 128;          // global col in [0,512)
    const float* W   = (n0 < 256) ? Wf : Wb;
    const float* bia = (n0 < 256) ? biasf : biasb;
    const int nc0 = n0 & 255;

    const int ty = tid >> 4, tx = tid & 15;
    const int arow = tid >> 3, akv = (tid & 7) << 2;
    const int bkr  = tid >> 5, bnv = (tid & 31) << 2;

    float acc[8][8];
    #pragma unroll
    for (int i = 0; i < 8; ++i)
        #pragma unroll
        for (int j = 0; j < 8; ++j) acc[i][j] = 0.f;

    for (int k0 = 0; k0 < 128; k0 += 32) {
        #pragma unroll
        for (int rr = 0; rr < 4; ++rr) {
            const int r = arow + rr * 32;
            const float4 av = *(const float4*)&A[(size_t)(m0 + r) * 128 + k0 + akv];
            As[akv + 0][r] = av.x; As[akv + 1][r] = av.y;
            As[akv + 2][r] = av.z; As[akv + 3][r] = av.w;
        }
        #pragma unroll
        for (int rr = 0; rr < 4; ++rr) {
            const int kr = bkr + rr * 8;
            *(float4*)&Bs[kr][bnv] =
                *(const float4*)&W[(size_t)(k0 + kr) * 256 + nc0 + bnv];
        }
        __syncthreads();
        #pragma unroll
        for (int k = 0; k < 32; ++k) {
            float av[8], bv[8];
            *(float4*)&av[0] = *(const float4*)&As[k][ty * 8];
            *(float4*)&av[4] = *(const float4*)&As[k][ty * 8 + 4];
            *(float4*)&bv[0] = *(const float4*)&Bs[k][tx * 8];
            *(float4*)&bv[4] = *(const float4*)&Bs[k][tx * 8 + 4];
            #pragma unroll
            for (int i = 0; i < 8; ++i)
                #pragma unroll
                for (int j = 0; j < 8; ++j)
                    acc[i][j] = __fmaf_rn(av[i], bv[j], acc[i][j]);
        }
        __syncthreads();
    }
    #pragma unroll
    for (int i = 0; i < 8; ++i) {
        const size_t rbase = (size_t)(m0 + ty * 8 + i) * 512 + n0 + tx * 8;
        float4 o;
        o.x = acc[i][0] + bia[nc0 + tx * 8 + 0];
        o.y = acc[i][1] + bia[nc0 + tx * 8 + 1];
        o.z = acc[i][2] + bia[nc0 + tx * 8 + 2];
        o.w = acc[i][3] + bia[nc0 + tx * 8 + 3];
        *(float4*)&Cout[rbase] = o;
        o.x = acc[i][4] + bia[nc0 + tx * 8 + 4];
        o.y = acc[i][5] + bia[nc0 + tx * 8 + 5];
        o.z = acc[i][6] + bia[nc0 + tx * 8 + 6];
        o.w = acc[i][7] + bia[nc0 + tx * 8 + 7];
        *(float4*)&Cout[rbase + 4] = o;
    }
}

// ---------------------------------------------------------------------------
// LSTM recurrence, LDS-only barriers. 256 blocks (batch x dir) x 512 threads.
// Wave w (0..7): kq = w&3 (K-quarter), gp = w>>2 (gates 2gp, 2gp+1).
// Lane = column 0..63. Phase A: every wave computes 2 gate-partials (16 FMA
// each) from BROADCAST float4 reads of hbuf, writes 2 coalesced zbuf rows.
// LDS_BAR. Phase B: wave 0 reads 16 partials/col, sums, gates, c/h update,
// writes double-buffered hbuf + fire-and-forget global h store. LDS_BAR.
// Global loads (xz prefetch) and stores (hout) are NEVER waited on in-loop.
// ---------------------------------------------------------------------------
__global__ __launch_bounds__(512, 1) void lstm_rec_2b(
    const float* __restrict__ xz, const float* __restrict__ Uf,
    const float* __restrict__ Ub, float* __restrict__ hout)
{
    const int b   = blockIdx.x & 127;
    const int dir = blockIdx.x >> 7;
    const int tid = threadIdx.x;
    const int lane = tid & 63;          // column 0..63
    const int w    = tid >> 6;          // wave 0..7
    const int kq   = w & 3;             // K-quarter
    const int gp   = w >> 2;            // gate pair: gates 2gp, 2gp+1
    const float* U = dir ? Ub : Uf;

    __shared__ float hbuf[2][64];
    __shared__ float zbuf[2][1024];     // [parity][kq*256 + gate*64 + col]

    // 32 U values: U[kq*16+j][g*64+lane], g = 2gp (a) and 2gp+1 (b). Named
    // scalars + asm pin => guaranteed VGPR-resident, not rematerializable.
    const float* Ua = U + (size_t)(kq * 16) * 256 + (2 * gp) * 64 + lane;
    const float* Ub_ = Ua + 64;
    float ua0 = Ua[0*256],  ua1 = Ua[1*256],  ua2 = Ua[2*256],  ua3 = Ua[3*256];
    float ua4 = Ua[4*256],  ua5 = Ua[5*256],  ua6 = Ua[6*256],  ua7 = Ua[7*256];
    float ua8 = Ua[8*256],  ua9 = Ua[9*256],  ua10 = Ua[10*256], ua11 = Ua[11*256];
    float ua12 = Ua[12*256], ua13 = Ua[13*256], ua14 = Ua[14*256], ua15 = Ua[15*256];
    float ub0 = Ub_[0*256],  ub1 = Ub_[1*256],  ub2 = Ub_[2*256],  ub3 = Ub_[3*256];
    float ub4 = Ub_[4*256],  ub5 = Ub_[5*256],  ub6 = Ub_[6*256],  ub7 = Ub_[7*256];
    float ub8 = Ub_[8*256],  ub9 = Ub_[9*256],  ub10 = Ub_[10*256], ub11 = Ub_[11*256];
    float ub12 = Ub_[12*256], ub13 = Ub_[13*256], ub14 = Ub_[14*256], ub15 = Ub_[15*256];
    asm volatile("" : "+v"(ua0), "+v"(ua1), "+v"(ua2), "+v"(ua3),
                      "+v"(ua4), "+v"(ua5), "+v"(ua6), "+v"(ua7),
                      "+v"(ua8), "+v"(ua9), "+v"(ua10), "+v"(ua11),
                      "+v"(ua12), "+v"(ua13), "+v"(ua14), "+v"(ua15));
    asm volatile("" : "+v"(ub0), "+v"(ub1), "+v"(ub2), "+v"(ub3),
                      "+v"(ub4), "+v"(ub5), "+v"(ub6), "+v"(ub7),
                      "+v"(ub8), "+v"(ub9), "+v"(ub10), "+v"(ub11),
                      "+v"(ub12), "+v"(ub13), "+v"(ub14), "+v"(ub15));

    if (tid < 64) hbuf[0][tid] = 0.f;
    float c = 0.f;
    __syncthreads();

    // xz columns for this wave's two gates (only kq==0 waves add x)
    const float* xzb = xz + (size_t)b * TT * 512 + (size_t)dir * 256
                          + (2 * gp) * 64 + lane;
    float* hob = hout + (size_t)b * TT * 128 + (size_t)dir * 64 + lane;

    int trow = dir ? (TT - 1) : 0;
    const int tstep = dir ? -1 : 1;
    float xca = 0.f, xcb = 0.f;
    if (kq == 0) { xca = xzb[(size_t)trow * 512]; xcb = xzb[(size_t)trow * 512 + 64]; }

    const int zsa = kq * 256 + (2 * gp) * 64 + lane;   // coalesced zbuf slots

    #pragma unroll 2
    for (int s = 0; s < TT; ++s) {
        const int p = s & 1;
        const int trn = trow + tstep;
        float xna = 0.f, xnb = 0.f;
        if (kq == 0 && s + 1 < TT) {        // prefetch: issued now, used next
            xna = xzb[(size_t)trn * 512];   // step; never drained by a barrier
            xnb = xzb[(size_t)trn * 512 + 64];
        }

        // phase A: two 16-FMA gate partials from broadcast h reads
        const float4 h0 = *(const float4*)&hbuf[p][kq * 16 + 0];
        const float4 h1 = *(const float4*)&hbuf[p][kq * 16 + 4];
        const float4 h2 = *(const float4*)&hbuf[p][kq * 16 + 8];
        const float4 h3 = *(const float4*)&hbuf[p][kq * 16 + 12];
        float s0 = 0.f, s1 = 0.f, s2 = 0.f, s3 = 0.f;
        float t0 = 0.f, t1 = 0.f, t2 = 0.f, t3 = 0.f;
        s0 = __fmaf_rn(h0.x, ua0,  s0); s1 = __fmaf_rn(h0.y, ua1,  s1);
        s2 = __fmaf_rn(h0.z, ua2,  s2); s3 = __fmaf_rn(h0.w, ua3,  s3);
        t0 = __fmaf_rn(h0.x, ub0,  t0); t1 = __fmaf_rn(h0.y, ub1,  t1);
        t2 = __fmaf_rn(h0.z, ub2,  t2); t3 = __fmaf_rn(h0.w, ub3,  t3);
        s0 = __fmaf_rn(h1.x, ua4,  s0); s1 = __fmaf_rn(h1.y, ua5,  s1);
        s2 = __fmaf_rn(h1.z, ua6,  s2); s3 = __fmaf_rn(h1.w, ua7,  s3);
        t0 = __fmaf_rn(h1.x, ub4,  t0); t1 = __fmaf_rn(h1.y, ub5,  t1);
        t2 = __fmaf_rn(h1.z, ub6,  t2); t3 = __fmaf_rn(h1.w, ub7,  t3);
        s0 = __fmaf_rn(h2.x, ua8,  s0); s1 = __fmaf_rn(h2.y, ua9,  s1);
        s2 = __fmaf_rn(h2.z, ua10, s2); s3 = __fmaf_rn(h2.w, ua11, s3);
        t0 = __fmaf_rn(h2.x, ub8,  t0); t1 = __fmaf_rn(h2.y, ub9,  t1);
        t2 = __fmaf_rn(h2.z, ub10, t2); t3 = __fmaf_rn(h2.w, ub11, t3);
        s0 = __fmaf_rn(h3.x, ua12, s0); s1 = __fmaf_rn(h3.y, ua13, s1);
        s2 = __fmaf_rn(h3.z, ua14, s2); s3 = __fmaf_rn(h3.w, ua15, s3);
        t0 = __fmaf_rn(h3.x, ub12, t0); t1 = __fmaf_rn(h3.y, ub13, t1);
        t2 = __fmaf_rn(h3.z, ub14, t2); t3 = __fmaf_rn(h3.w, ub15, t3);
        float za = (s0 + s1) + (s2 + s3);
        float zb = (t0 + t1) + (t2 + t3);
        if (kq == 0) { za += xca; zb += xcb; }
        zbuf[p][zsa]      = za;
        zbuf[p][zsa + 64] = zb;

        LDS_BAR();

        if (w == 0) {   // phase B: wave 0 finishes all 64 columns
            const float* zp = zbuf[p];
            const float z0 = ((zp[lane]       + zp[256 + lane])
                            + (zp[512 + lane] + zp[768 + lane]));
            const float z1 = ((zp[64 + lane]       + zp[256 + 64 + lane])
                            + (zp[512 + 64 + lane] + zp[768 + 64 + lane]));
            const float z2 = ((zp[128 + lane]       + zp[256 + 128 + lane])
                            + (zp[512 + 128 + lane] + zp[768 + 128 + lane]));
            const float z3 = ((zp[192 + lane]       + zp[256 + 192 + lane])
                            + (zp[512 + 192 + lane] + zp[768 + 192 + lane]));
            const float gi = sigf(z0);
            const float gf = sigf(z1);
            const float gg = fmaxf(z2, 0.f);
            const float go = sigf(z3);
            c = gf * c + gi * gg;
            const float h = go * fmaxf(c, 0.f);
            hbuf[p ^ 1][lane] = h;
            hob[(size_t)trow * 128] = h;   // fire-and-forget, never drained
        }

        LDS_BAR();

        xca = xna; xcb = xnb;
        trow = trn;
    }
}

// ---------------------------------------------------------------------------
// Dense + softmax: out[m][c] = softmax_c( h2[m][:] @ Wd[:,c] + bd[c] )
// ---------------------------------------------------------------------------
__global__ __launch_bounds__(256) void dense_softmax(
    const float* __restrict__ h2, const float* __restrict__ Wd,
    const float* __restrict__ bd, float* __restrict__ out)
{
    __shared__ float Wl[128 * 45];
    __shared__ float bl[48];
    __shared__ float hrow[4][128];
    const int tid = threadIdx.x;
    for (int i = tid; i < 128 * 45; i += 256) Wl[i] = Wd[i];
    if (tid < 45) bl[tid] = bd[tid];
    __syncthreads();

    const int w = tid >> 6, l = tid & 63;
    const size_t row0 = (size_t)blockIdx.x * 64;
    for (int rr = 0; rr < 16; ++rr) {
        const size_t m = row0 + (size_t)rr * 4 + w;
        const float2 hv = *(const float2*)&h2[m * 128 + l * 2];
        hrow[w][l * 2] = hv.x;
        hrow[w][l * 2 + 1] = hv.y;
        __syncthreads();
        float lg = -3.0e38f;
        if (l < CC) {
            lg = bl[l];
            #pragma unroll 8
            for (int k = 0; k < 128; ++k) lg = __fmaf_rn(hrow[w][k], Wl[k * 45 + l], lg);
        }
        float mx = lg;
        #pragma unroll
        for (int off = 32; off >= 1; off >>= 1) mx = fmaxf(mx, __shfl_xor(mx, off));
        const float e = (l < CC) ? __expf(lg - mx) : 0.f;
        float sm = e;
        #pragma unroll
        for (int off = 32; off >= 1; off >>= 1) sm += __shfl_xor(sm, off);
        if (l < CC) out[m * 45 + l] = e / sm;
        __syncthreads();
    }
}

// ---------------------------------------------------------------------------
extern "C" void kernel_launch(void* const* d_in, const int* in_sizes, int n_in,
                              void* d_out, int out_size, void* d_ws, size_t ws_size,
                              hipStream_t stream)
{
    const float* x   = (const float*)d_in[0];
    const float* W1f = (const float*)d_in[1];
    const float* U1f = (const float*)d_in[2];
    const float* b1f = (const float*)d_in[3];
    const float* W1b = (const float*)d_in[4];
    const float* U1b = (const float*)d_in[5];
    const float* b1b = (const float*)d_in[6];
    const float* W2f = (const float*)d_in[7];
    const float* U2f = (const float*)d_in[8];
    const float* b2f = (const float*)d_in[9];
    const float* W2b = (const float*)d_in[10];
    const float* U2b = (const float*)d_in[11];
    const float* b2b = (const float*)d_in[12];
    const float* Wd  = (const float*)d_in[13];
    const float* bd  = (const float*)d_in[14];

    // Workspace layout (160 MiB):
    //   xz : 65536 x 512 f32 = 128 MiB   (reused by layer 1 and layer 2)
    //   h  : 65536 x 128 f32 =  32 MiB   (h1, then overwritten by h2)
    float* xz = (float*)d_ws;
    float* h  = (float*)((char*)d_ws + (size_t)65536 * 512 * 4);

    const dim3 gemm_grid(512, 4);      // 65536/128 m-tiles, 512/128 n-tiles
    const dim3 rec_grid(256);          // 128 batch x 2 directions
    const dim3 dense_grid(1024);       // 65536/64 rows

    // Layer 1
    gemm_xz<<<gemm_grid, dim3(256), 0, stream>>>(x, W1f, W1b, b1f, b1b, xz);
    lstm_rec_2b<<<rec_grid, dim3(512), 0, stream>>>(xz, U1f, U1b, h);
    // Layer 2
    gemm_xz<<<gemm_grid, dim3(256), 0, stream>>>(h, W2f, W2b, b2f, b2b, xz);
    lstm_rec_2b<<<rec_grid, dim3(512), 0, stream>>>(xz, U2f, U2b, h);
    // Head
    dense_softmax<<<dense_grid, dim3(256), 0, stream>>>(h, Wd, bd, (float*)d_out);
}